// Round 13
// baseline (246.039 us; speedup 1.0000x reference)
//
#include <hip/hip_runtime.h>

#define N_NODES 100000
#define N_TYPES 7
#define N_EDGES 400000
#define DIM 128
#define NTOT (N_TYPES * N_NODES)   // 700000
#define ETOT (N_TYPES * N_EDGES)   // 2800000

// bucketed CSR build
#define RBITS 10
#define RNODE 1024
#define NBUCK 98                   // ceil(N_NODES / RNODE)
#define NTB (N_TYPES * NBUCK)      // 686
#define BSTRIDE 128                // padded bucket stride per type
#define CAP 6144                   // per-bucket capacity (mean 4082, +32 sigma)
#define CHUNK 2048
#define NCHUNKS ((N_EDGES + CHUNK - 1) / CHUNK)   // 196

typedef short v8s __attribute__((ext_vector_type(8)));   // 8 bf16 (4 VGPRs)
typedef float v4f __attribute__((ext_vector_type(4)));   // 4 f32 acc

__device__ __forceinline__ unsigned short f2bf(float f) {
    unsigned int x = __float_as_uint(f);
    return (unsigned short)((x + 0x7FFFu + ((x >> 16) & 1u)) >> 16);   // RNE
}

// ---------------------------------------------------------------------------
// casts
// ---------------------------------------------------------------------------
__global__ __launch_bounds__(256) void cast_x_kernel(
    const float* __restrict__ x, unsigned short* __restrict__ xb)
{
    int i = blockIdx.x * 256 + threadIdx.x;            // one float4 each
    if (i >= N_NODES * DIM / 4) return;
    float4 v = reinterpret_cast<const float4*>(x)[i];
    ushort4 o;
    o.x = f2bf(v.x); o.y = f2bf(v.y); o.z = f2bf(v.z); o.w = f2bf(v.w);
    reinterpret_cast<ushort4*>(xb)[i] = o;
}

// blocks 0..447: WT[t][j][k] = bf16(W[t][k][j]); block 448: bsum
__global__ __launch_bounds__(256) void cast_wt_bsum_kernel(
    const float* __restrict__ W, const float* __restrict__ b,
    unsigned short* __restrict__ WT, float* __restrict__ bsum)
{
    if (blockIdx.x == 448) {
        int j = threadIdx.x;
        if (j < DIM) {
            float s = 0.f;
            for (int t = 0; t < N_TYPES; ++t) s += b[t * DIM + j];
            bsum[j] = s;
        }
        return;
    }
    int i = blockIdx.x * 256 + threadIdx.x;
    if (i >= N_TYPES * DIM * DIM) return;
    int t = i >> 14, r = i & 16383, j = r >> 7, k = r & 127;
    WT[i] = f2bf(W[(t << 14) + (k << 7) + j]);
}

// ---------------------------------------------------------------------------
// binpass: LDS-sort each 2048-edge chunk by bucket (dst>>10), write each
// bucket's run contiguously. Entry = (dst&1023)<<17 | src.
// After this kernel, gcur[t*BSTRIDE+b] = bucket edge count.
// ---------------------------------------------------------------------------
__global__ __launch_bounds__(256) void binpass_kernel(
    const int* __restrict__ ei, int* __restrict__ gcur,
    unsigned int* __restrict__ bucketbuf)
{
    __shared__ unsigned int packedLds[CHUNK];
    __shared__ unsigned char bLds[CHUNK];
    __shared__ unsigned int sortedLds[CHUNK];
    __shared__ int cnt[BSTRIDE];
    __shared__ int lofs[BSTRIDE];
    __shared__ int gbase[BSTRIDE];

    const int blk = blockIdx.x;
    const int t = blk / NCHUNKS;
    const int c = blk - t * NCHUNKS;
    const int* srcp = ei + (size_t)t * 2 * N_EDGES;
    const int* dstp = srcp + N_EDGES;
    const int e0 = c * CHUNK;
    const int e1 = min(e0 + CHUNK, N_EDGES);
    const int tid = threadIdx.x;

    if (tid < BSTRIDE) cnt[tid] = 0;
    __syncthreads();

#pragma unroll
    for (int k = 0; k < CHUNK / 256; ++k) {
        int j = tid + k * 256;
        int e = e0 + j;
        unsigned char b = 0xFF;
        unsigned int pk = 0;
        if (e < e1) {
            int s = srcp[e];
            int d = dstp[e];
            b = (unsigned char)(d >> RBITS);
            pk = ((unsigned int)(d & (RNODE - 1)) << 17) | (unsigned int)s;
            atomicAdd(&cnt[b], 1);
        }
        packedLds[j] = pk;
        bLds[j] = b;
    }
    __syncthreads();

    if (tid < BSTRIDE) lofs[tid] = cnt[tid];
    __syncthreads();
    for (int off = 1; off < BSTRIDE; off <<= 1) {
        int tv = 0;
        if (tid >= off && tid < BSTRIDE) tv = lofs[tid - off];
        __syncthreads();
        if (tid < BSTRIDE) lofs[tid] += tv;
        __syncthreads();
    }
    if (tid < BSTRIDE) lofs[tid] -= cnt[tid];
    __syncthreads();

    if (tid < BSTRIDE) {
        int n = cnt[tid];
        int base = -1;
        if (n > 0 && tid < NBUCK) {
            int rel = atomicAdd(&gcur[t * BSTRIDE + tid], n);
            base = (t * BSTRIDE + tid) * CAP + rel;
        }
        gbase[tid] = base;
        cnt[tid] = lofs[tid];
    }
    __syncthreads();

#pragma unroll
    for (int k = 0; k < CHUNK / 256; ++k) {
        int j = tid + k * 256;
        unsigned char b = bLds[j];
        if (b != 0xFF) {
            int p = atomicAdd(&cnt[b], 1);
            sortedLds[p] = packedLds[j];
        }
    }
    __syncthreads();

    const int wave = tid >> 6, lane = tid & 63;
    for (int b = wave * 32; b < wave * 32 + 32; ++b) {
        if (b >= NBUCK) break;
        int base = gbase[b];
        if (base < 0) continue;
        int o = lofs[b];
        int n = cnt[b] - o;
        for (int i = lane; i < n; i += 64)
            bucketbuf[(size_t)base + i] = sortedLds[o + i];
    }
}

// ---------------------------------------------------------------------------
// bucket_base: exclusive scan of the 686 bucket counts (from gcur, stride
// BSTRIDE) -> sbase[t*NBUCK+b] = first edge index of bucket. Also sets
// offs[NTOT] = ETOT.
// ---------------------------------------------------------------------------
__global__ __launch_bounds__(1024) void bucket_base_kernel(
    const int* __restrict__ gcur, int* __restrict__ sbase, int* __restrict__ offs)
{
    __shared__ int s[1024];
    int tid = threadIdx.x;
    int v = 0;
    if (tid < NTB) {
        int t = tid / NBUCK, b = tid - t * NBUCK;
        v = min(gcur[t * BSTRIDE + b], CAP);
    }
    s[tid] = v;
    __syncthreads();
    for (int off = 1; off < 1024; off <<= 1) {
        int t2 = (tid >= off) ? s[tid - off] : 0;
        __syncthreads();
        s[tid] += t2;
        __syncthreads();
    }
    if (tid < NTB) sbase[tid] = s[tid] - v;   // exclusive
    if (tid == 0) offs[NTOT] = ETOT;
}

// ---------------------------------------------------------------------------
// hist_place: per (type,bucket), ONE LDS load of the bucket serves both the
// degree-histogram (-> offs, with bucket base folded in) and the
// counting-sort placement (-> srcperm, coalesced). Merges the former
// bucket_hist_scan + scan3 + place (one bucketbuf re-read eliminated).
// LDS: 24 + 24 + 4 + 1 KB = 53 KB.
// ---------------------------------------------------------------------------
__global__ __launch_bounds__(256) void hist_place_kernel(
    const unsigned int* __restrict__ bucketbuf, const int* __restrict__ gcur,
    const int* __restrict__ sbase,
    int* __restrict__ offs, int* __restrict__ srcperm)
{
    __shared__ unsigned int sorted[CAP];
    __shared__ unsigned int sorted2[CAP];
    __shared__ int cnt[RNODE];
    __shared__ int s[256];

    const int blk = blockIdx.x;
    const int t = blk / NBUCK;
    const int b = blk - t * NBUCK;
    const int n = min(gcur[t * BSTRIDE + b], CAP);
    const int ebase = sbase[blk];              // first edge index of bucket
    const int g0 = b << RBITS;
    const int validR = min(RNODE, N_NODES - g0);
    const int tid = threadIdx.x;

    // load bucket into LDS; zero counters
    const unsigned int* bb = bucketbuf + (size_t)(t * BSTRIDE + b) * CAP;
    for (int i = tid; i < n; i += 256) sorted[i] = bb[i];
    for (int j = tid; j < RNODE; j += 256) cnt[j] = 0;
    __syncthreads();

    // histogram
    for (int i = tid; i < n; i += 256)
        atomicAdd(&cnt[sorted[i] >> 17], 1);
    __syncthreads();

    // local exclusive scan of cnt[1024] (4/thread); write offs; cnt -> cursors
    int base4 = tid * 4;
    int v[4], tot = 0;
#pragma unroll
    for (int k = 0; k < 4; ++k) { v[k] = cnt[base4 + k]; tot += v[k]; }
    s[tid] = tot;
    __syncthreads();
    for (int off = 1; off < 256; off <<= 1) {
        int t2 = (tid >= off) ? s[tid - off] : 0;
        __syncthreads();
        s[tid] += t2;
        __syncthreads();
    }
    int run = s[tid] - tot;
    int* og = offs + (size_t)t * N_NODES + g0;
#pragma unroll
    for (int k = 0; k < 4; ++k) {
        if (base4 + k < validR) og[base4 + k] = ebase + run;
        cnt[base4 + k] = run;                  // cursor (own slots only)
        run += v[k];
    }
    __syncthreads();

    // counting-sort into sorted2
    for (int i = tid; i < n; i += 256) {
        unsigned int pk = sorted[i];
        int p = atomicAdd(&cnt[pk >> 17], 1);
        sorted2[p] = pk & 0x1FFFFu;
    }
    __syncthreads();

    // coalesced write-out
    int* outp = srcperm + ebase;
    for (int i = tid; i < n; i += 256) outp[i] = (int)sorted2[i];
}

// ---------------------------------------------------------------------------
// Aggregate (unchanged from round 12): 16 lanes per (type,node) group ->
// 4 independent CSR chains per wave, predicated to the wave-max degree.
// ---------------------------------------------------------------------------
__global__ __launch_bounds__(256) void aggregate_kernel(
    const unsigned short* __restrict__ xb,
    const int* __restrict__ offs,       // [NTOT+1], contiguous over (t,g)
    const int* __restrict__ srcperm,
    unsigned short* __restrict__ meanout,
    int grp0, int ngrp)
{
    int gi = blockIdx.x * 16 + (threadIdx.x >> 4);
    if (gi >= ngrp) return;
    int grp = grp0 + gi;
    int l = threadIdx.x & 15;

    int beg = offs[grp];
    int end = offs[grp + 1];
    int m = end - beg;

    int mm = m;
    mm = max(mm, __shfl_xor(mm, 16));
    mm = max(mm, __shfl_xor(mm, 32));

    float a[8];
#pragma unroll
    for (int j = 0; j < 8; ++j) a[j] = 0.f;

    const int eSafe = min(beg, ETOT - 1);
#pragma unroll 4
    for (int i = 0; i < mm; ++i) {
        bool valid = i < m;
        int e = valid ? (beg + i) : eSafe;
        int s = srcperm[e];
        uint4 v = *reinterpret_cast<const uint4*>(
            reinterpret_cast<const char*>(xb) + ((size_t)s << 8) + (l << 4));
        float w = valid ? 1.f : 0.f;
        a[0] += w * __uint_as_float(v.x << 16);
        a[1] += w * __uint_as_float(v.x & 0xFFFF0000u);
        a[2] += w * __uint_as_float(v.y << 16);
        a[3] += w * __uint_as_float(v.y & 0xFFFF0000u);
        a[4] += w * __uint_as_float(v.z << 16);
        a[5] += w * __uint_as_float(v.z & 0xFFFF0000u);
        a[6] += w * __uint_as_float(v.w << 16);
        a[7] += w * __uint_as_float(v.w & 0xFFFF0000u);
    }

    float inv = 1.0f / fmaxf((float)m, 1.0f);
    unsigned int p0, p1, p2, p3;
    asm("v_cvt_pk_bf16_f32 %0, %1, %2" : "=v"(p0) : "v"(a[0] * inv), "v"(a[1] * inv));
    asm("v_cvt_pk_bf16_f32 %0, %1, %2" : "=v"(p1) : "v"(a[2] * inv), "v"(a[3] * inv));
    asm("v_cvt_pk_bf16_f32 %0, %1, %2" : "=v"(p2) : "v"(a[4] * inv), "v"(a[5] * inv));
    asm("v_cvt_pk_bf16_f32 %0, %1, %2" : "=v"(p3) : "v"(a[6] * inv), "v"(a[7] * inv));
    uint4 o = make_uint4(p0, p1, p2, p3);
    *reinterpret_cast<uint4*>(
        reinterpret_cast<char*>(meanout) + ((size_t)gi << 8) + (l << 4)) = o;
}

// ---------------------------------------------------------------------------
// MFMA GEMM: 128 rows/block (2 row-tiles per wave) -> WT staging traffic
// halved, barriers amortized 2x. B staged in LDS, XOR-swizzled.
// ---------------------------------------------------------------------------
__global__ __launch_bounds__(256) void matmul_kernel(
    const unsigned short* __restrict__ meanall, size_t meanStride,
    int t0, int nt,
    const unsigned short* __restrict__ WT,
    const float* __restrict__ bsum,
    float* __restrict__ out, int accum)
{
    __shared__ unsigned short sB[DIM * DIM];   // 32 KB, swizzled

    const int tid = threadIdx.x;
    const int wave = tid >> 6;
    const int lane = tid & 63;
    const int rlo = lane & 15;
    const int khi = lane >> 4;                 // 0..3
    const int row0 = blockIdx.x * 128 + wave * 16;   // tile A rows; tile B = +64

    v4f acc[2][8];
#pragma unroll
    for (int u = 0; u < 2; ++u)
#pragma unroll
        for (int n = 0; n < 8; ++n) acc[u][n] = (v4f){0.f, 0.f, 0.f, 0.f};

    int rowA0 = row0 + rlo;       if (rowA0 >= N_NODES) rowA0 = N_NODES - 1;
    int rowA1 = row0 + 64 + rlo;  if (rowA1 >= N_NODES) rowA1 = N_NODES - 1;

    for (int tt = 0; tt < nt; ++tt) {
        int t = t0 + tt;
        __syncthreads();
        const uint4* gw = reinterpret_cast<const uint4*>(WT + ((size_t)t << 14));
#pragma unroll
        for (int i = 0; i < 8; ++i) {
            int c = tid + (i << 8);            // 0..2047
            uint4 v = gw[c];
            int L = c << 4;
            int row = L >> 8;
            int sb = (row << 8) | ((L & 255) ^ ((row & 7) << 4));
            *reinterpret_cast<uint4*>(reinterpret_cast<char*>(sB) + sb) = v;
        }
        __syncthreads();

        const unsigned short* ar0 = meanall + (size_t)tt * meanStride + ((size_t)rowA0 << 7);
        const unsigned short* ar1 = meanall + (size_t)tt * meanStride + ((size_t)rowA1 << 7);

#pragma unroll
        for (int k0 = 0; k0 < DIM; k0 += 32) {
            v8s a0 = *reinterpret_cast<const v8s*>(ar0 + k0 + (khi << 3));
            v8s a1 = *reinterpret_cast<const v8s*>(ar1 + k0 + (khi << 3));
#pragma unroll
            for (int n = 0; n < 8; ++n) {
                int jrow = (n << 4) | rlo;
                int kb = (k0 + (khi << 3)) << 1;
                int sb = (jrow << 8) | (kb ^ ((jrow & 7) << 4));
                v8s bf = *reinterpret_cast<const v8s*>(reinterpret_cast<char*>(sB) + sb);
                acc[0][n] = __builtin_amdgcn_mfma_f32_16x16x32_bf16(a0, bf, acc[0][n], 0, 0, 0);
                acc[1][n] = __builtin_amdgcn_mfma_f32_16x16x32_bf16(a1, bf, acc[1][n], 0, 0, 0);
            }
        }
    }

    const float inv7 = 1.0f / 7.0f;
#pragma unroll
    for (int u = 0; u < 2; ++u) {
#pragma unroll
        for (int n = 0; n < 8; ++n) {
            int col = (n << 4) | rlo;
            float bs = bsum[col];
#pragma unroll
            for (int r = 0; r < 4; ++r) {
                int row = row0 + u * 64 + (khi << 2) + r;
                if (row < N_NODES) {
                    float* p = out + ((size_t)row << 7) + col;
                    if (accum) *p += acc[u][n][r] * inv7;
                    else       *p = (acc[u][n][r] + bs) * inv7;
                }
            }
        }
    }
}

__global__ __launch_bounds__(256) void out_init_kernel(
    const float* __restrict__ bsum, float* __restrict__ out)
{
    int i = blockIdx.x * 256 + threadIdx.x;
    if (i >= N_NODES * DIM / 4) return;
    int c4 = (i & 31) * 4;
    const float inv7 = 1.0f / 7.0f;
    float4 bv = *reinterpret_cast<const float4*>(bsum + c4);
    float4 o = make_float4(bv.x * inv7, bv.y * inv7, bv.z * inv7, bv.w * inv7);
    reinterpret_cast<float4*>(out)[i] = o;
}

extern "C" void kernel_launch(void* const* d_in, const int* in_sizes, int n_in,
                              void* d_out, int out_size, void* d_ws, size_t ws_size,
                              hipStream_t stream) {
    const float* x  = (const float*)d_in[0];
    const int*   ei = (const int*)d_in[1];     // [N_TYPES, 2, N_EDGES] int32
    const float* W  = (const float*)d_in[2];
    const float* b  = (const float*)d_in[3];
    float* out = (float*)d_out;

    // ---- workspace layout ----
    char* p = (char*)d_ws;
    unsigned short* xb = (unsigned short*)p;          p += (size_t)N_NODES * DIM * 2;       // 25.6 MB
    unsigned short* WT = (unsigned short*)p;          p += (size_t)N_TYPES * DIM * DIM * 2; // 229 KB
    float* bsum = (float*)p;                          p += 512;
    int* srcperm = (int*)p;                           p += (size_t)ETOT * 4;                // 11.2 MB
    int* offs = (int*)p;                              p += (size_t)(NTOT + 1) * 4;          // 2.8 MB
    int* sbase = (int*)p;                             p += 1024 * 4;
    int* gcur = (int*)p;                              p += (size_t)N_TYPES * BSTRIDE * 4;
    p = (char*)(((uintptr_t)p + 15) & ~(uintptr_t)15);
    unsigned int* bucketbuf = (unsigned int*)p;       // 22 MB (dead before meanbuf live)
    unsigned short* meanbuf = (unsigned short*)p;
    size_t mean1_bytes = (size_t)N_NODES * DIM * 2;   // 25.6 MB per type
    size_t used = (size_t)(p - (char*)d_ws);
    size_t bucket_bytes = (size_t)N_TYPES * BSTRIDE * CAP * 4;
    bool fused = (ws_size >= used + 7 * mean1_bytes) &&
                 (7 * mean1_bytes >= bucket_bytes);

    cast_x_kernel<<<(N_NODES * DIM / 4 + 255) / 256, 256, 0, stream>>>(x, xb);
    cast_wt_bsum_kernel<<<449, 256, 0, stream>>>(W, b, WT, bsum);

    hipMemsetAsync(gcur, 0, (size_t)N_TYPES * BSTRIDE * 4, stream);
    binpass_kernel<<<N_TYPES * NCHUNKS, 256, 0, stream>>>(ei, gcur, bucketbuf);
    bucket_base_kernel<<<1, 1024, 0, stream>>>(gcur, sbase, offs);
    hist_place_kernel<<<NTB, 256, 0, stream>>>(bucketbuf, gcur, sbase, offs, srcperm);

    const int matmul_blocks = (N_NODES + 127) / 128;  // 782

    if (fused) {
        size_t meanStride = (size_t)N_NODES * DIM;    // ushorts
        aggregate_kernel<<<(NTOT + 15) / 16, 256, 0, stream>>>(
            xb, offs, srcperm, meanbuf, 0, NTOT);
        matmul_kernel<<<matmul_blocks, 256, 0, stream>>>(
            meanbuf, meanStride, 0, N_TYPES, WT, bsum, out, 0);
    } else {
        out_init_kernel<<<(N_NODES * DIM / 4 + 255) / 256, 256, 0, stream>>>(bsum, out);
        for (int t = 0; t < N_TYPES; ++t) {
            aggregate_kernel<<<(N_NODES + 15) / 16, 256, 0, stream>>>(
                xb, offs, srcperm, meanbuf, t * N_NODES, N_NODES);
            matmul_kernel<<<matmul_blocks, 256, 0, stream>>>(
                meanbuf, 0, t, 1, WT, bsum, out, 1);
        }
    }
}

// Round 14
// 232.017 us; speedup vs baseline: 1.0604x; 1.0604x over previous
//
#include <hip/hip_runtime.h>

#define N_NODES 100000
#define N_TYPES 7
#define N_EDGES 400000
#define DIM 128
#define NTOT (N_TYPES * N_NODES)   // 700000
#define ETOT (N_TYPES * N_EDGES)   // 2800000

// bucketed CSR build
#define RBITS 10
#define RNODE 1024
#define NBUCK 98                   // ceil(N_NODES / RNODE)
#define NTB (N_TYPES * NBUCK)      // 686
#define BSTRIDE 128                // padded bucket stride per type
#define CAP 4992                   // per-bucket capacity (mean 4096, +14 sigma)
#define CHUNK 2048
#define NCHUNKS ((N_EDGES + CHUNK - 1) / CHUNK)   // 196

typedef short v8s __attribute__((ext_vector_type(8)));   // 8 bf16 (4 VGPRs)
typedef float v4f __attribute__((ext_vector_type(4)));   // 4 f32 acc

__device__ __forceinline__ unsigned short f2bf(float f) {
    unsigned int x = __float_as_uint(f);
    return (unsigned short)((x + 0x7FFFu + ((x >> 16) & 1u)) >> 16);   // RNE
}

// ---------------------------------------------------------------------------
// prep: blocks [0,12500) cast x -> bf16; [12500,12948) transpose-cast W;
// 12948: bias sum; 12949: zero gcur. One launch replaces three + a memset.
// ---------------------------------------------------------------------------
#define XBLOCKS 12500
__global__ __launch_bounds__(256) void prep_kernel(
    const float* __restrict__ x, const float* __restrict__ W,
    const float* __restrict__ b,
    unsigned short* __restrict__ xb, unsigned short* __restrict__ WT,
    float* __restrict__ bsum, int* __restrict__ gcur)
{
    int blk = blockIdx.x;
    if (blk < XBLOCKS) {
        int i = blk * 256 + threadIdx.x;                 // one float4 each
        if (i >= N_NODES * DIM / 4) return;
        float4 v = reinterpret_cast<const float4*>(x)[i];
        ushort4 o;
        o.x = f2bf(v.x); o.y = f2bf(v.y); o.z = f2bf(v.z); o.w = f2bf(v.w);
        reinterpret_cast<ushort4*>(xb)[i] = o;
        return;
    }
    int j = blk - XBLOCKS;
    if (j < 448) {
        int i = j * 256 + threadIdx.x;
        if (i >= N_TYPES * DIM * DIM) return;
        int t = i >> 14, r = i & 16383, jj = r >> 7, k = r & 127;
        WT[i] = f2bf(W[(t << 14) + (k << 7) + jj]);
        return;
    }
    if (j == 448) {
        int c = threadIdx.x;
        if (c < DIM) {
            float s = 0.f;
            for (int t = 0; t < N_TYPES; ++t) s += b[t * DIM + c];
            bsum[c] = s;
        }
        return;
    }
    // j == 449: zero gcur (896 ints)
    for (int i = threadIdx.x; i < N_TYPES * BSTRIDE; i += 256) gcur[i] = 0;
}

// ---------------------------------------------------------------------------
// binpass: LDS-sort each 2048-edge chunk by bucket (dst>>10), write each
// bucket's run contiguously. Entry = (dst&1023)<<17 | src.
// After this kernel, gcur[t*BSTRIDE+b] = bucket edge count.
// ---------------------------------------------------------------------------
__global__ __launch_bounds__(256) void binpass_kernel(
    const int* __restrict__ ei, int* __restrict__ gcur,
    unsigned int* __restrict__ bucketbuf)
{
    __shared__ unsigned int packedLds[CHUNK];
    __shared__ unsigned char bLds[CHUNK];
    __shared__ unsigned int sortedLds[CHUNK];
    __shared__ int cnt[BSTRIDE];
    __shared__ int lofs[BSTRIDE];
    __shared__ int gbase[BSTRIDE];

    const int blk = blockIdx.x;
    const int t = blk / NCHUNKS;
    const int c = blk - t * NCHUNKS;
    const int* srcp = ei + (size_t)t * 2 * N_EDGES;
    const int* dstp = srcp + N_EDGES;
    const int e0 = c * CHUNK;
    const int e1 = min(e0 + CHUNK, N_EDGES);
    const int tid = threadIdx.x;

    if (tid < BSTRIDE) cnt[tid] = 0;
    __syncthreads();

#pragma unroll
    for (int k = 0; k < CHUNK / 256; ++k) {
        int j = tid + k * 256;
        int e = e0 + j;
        unsigned char b = 0xFF;
        unsigned int pk = 0;
        if (e < e1) {
            int s = srcp[e];
            int d = dstp[e];
            b = (unsigned char)(d >> RBITS);
            pk = ((unsigned int)(d & (RNODE - 1)) << 17) | (unsigned int)s;
            atomicAdd(&cnt[b], 1);
        }
        packedLds[j] = pk;
        bLds[j] = b;
    }
    __syncthreads();

    if (tid < BSTRIDE) lofs[tid] = cnt[tid];
    __syncthreads();
    for (int off = 1; off < BSTRIDE; off <<= 1) {
        int tv = 0;
        if (tid >= off && tid < BSTRIDE) tv = lofs[tid - off];
        __syncthreads();
        if (tid < BSTRIDE) lofs[tid] += tv;
        __syncthreads();
    }
    if (tid < BSTRIDE) lofs[tid] -= cnt[tid];
    __syncthreads();

    if (tid < BSTRIDE) {
        int n = cnt[tid];
        int base = -1;
        if (n > 0 && tid < NBUCK) {
            int rel = atomicAdd(&gcur[t * BSTRIDE + tid], n);
            base = (t * BSTRIDE + tid) * CAP + rel;
        }
        gbase[tid] = base;
        cnt[tid] = lofs[tid];
    }
    __syncthreads();

#pragma unroll
    for (int k = 0; k < CHUNK / 256; ++k) {
        int j = tid + k * 256;
        unsigned char b = bLds[j];
        if (b != 0xFF) {
            int p = atomicAdd(&cnt[b], 1);
            sortedLds[p] = packedLds[j];
        }
    }
    __syncthreads();

    const int wave = tid >> 6, lane = tid & 63;
    for (int b = wave * 32; b < wave * 32 + 32; ++b) {
        if (b >= NBUCK) break;
        int base = gbase[b];
        if (base < 0) continue;
        int o = lofs[b];
        int n = cnt[b] - o;
        for (int i = lane; i < n; i += 64)
            bucketbuf[(size_t)base + i] = sortedLds[o + i];
    }
}

// ---------------------------------------------------------------------------
// hist_place: per (type,bucket), ONE LDS load of the bucket serves both the
// degree-histogram (-> offs, bucket base folded in) and the counting-sort
// placement (-> srcperm, coalesced). Bucket edge-base computed in-block by
// a parallel sum over the (cached) 686 bucket counts. LDS 44 KB -> 3 blk/CU.
// ---------------------------------------------------------------------------
__global__ __launch_bounds__(256) void hist_place_kernel(
    const unsigned int* __restrict__ bucketbuf, const int* __restrict__ gcur,
    int* __restrict__ offs, int* __restrict__ srcperm)
{
    __shared__ unsigned int sorted[CAP];
    __shared__ unsigned int sorted2[CAP];
    __shared__ int cnt[RNODE];
    __shared__ int s[256];
    __shared__ int ebaseS;

    const int blk = blockIdx.x;
    const int t = blk / NBUCK;
    const int b = blk - t * NBUCK;
    const int n = min(gcur[t * BSTRIDE + b], CAP);
    const int g0 = b << RBITS;
    const int validR = min(RNODE, N_NODES - g0);
    const int tid = threadIdx.x;

    // exclusive prefix over earlier buckets -> ebase (parallel partial sums)
    {
        int partial = 0;
        for (int i = tid; i < blk; i += 256) {
            int tt = i / NBUCK, bb = i - tt * NBUCK;
            partial += min(gcur[tt * BSTRIDE + bb], CAP);
        }
        s[tid] = partial;
        __syncthreads();
        for (int off = 128; off > 0; off >>= 1) {
            if (tid < off) s[tid] += s[tid + off];
            __syncthreads();
        }
        if (tid == 0) ebaseS = s[0];
        __syncthreads();
    }
    const int ebase = ebaseS;
    if (blk == 0 && tid == 0) offs[NTOT] = ETOT;

    // load bucket into LDS; zero counters
    const unsigned int* bb2 = bucketbuf + (size_t)(t * BSTRIDE + b) * CAP;
    for (int i = tid; i < n; i += 256) sorted[i] = bb2[i];
    for (int j = tid; j < RNODE; j += 256) cnt[j] = 0;
    __syncthreads();

    // histogram
    for (int i = tid; i < n; i += 256)
        atomicAdd(&cnt[sorted[i] >> 17], 1);
    __syncthreads();

    // local exclusive scan of cnt[1024] (4/thread); write offs; cnt -> cursors
    int base4 = tid * 4;
    int v[4], tot = 0;
#pragma unroll
    for (int k = 0; k < 4; ++k) { v[k] = cnt[base4 + k]; tot += v[k]; }
    s[tid] = tot;
    __syncthreads();
    for (int off = 1; off < 256; off <<= 1) {
        int t2 = (tid >= off) ? s[tid - off] : 0;
        __syncthreads();
        s[tid] += t2;
        __syncthreads();
    }
    int run = s[tid] - tot;
    int* og = offs + (size_t)t * N_NODES + g0;
#pragma unroll
    for (int k = 0; k < 4; ++k) {
        if (base4 + k < validR) og[base4 + k] = ebase + run;
        cnt[base4 + k] = run;                  // cursor (own slots only)
        run += v[k];
    }
    __syncthreads();

    // counting-sort into sorted2
    for (int i = tid; i < n; i += 256) {
        unsigned int pk = sorted[i];
        int p = atomicAdd(&cnt[pk >> 17], 1);
        sorted2[p] = pk & 0x1FFFFu;
    }
    __syncthreads();

    // coalesced write-out
    int* outp = srcperm + ebase;
    for (int i = tid; i < n; i += 256) outp[i] = (int)sorted2[i];
}

// ---------------------------------------------------------------------------
// Aggregate (unchanged): 16 lanes per (type,node) group -> 4 independent CSR
// chains per wave, predicated to the wave-max degree.
// ---------------------------------------------------------------------------
__global__ __launch_bounds__(256) void aggregate_kernel(
    const unsigned short* __restrict__ xb,
    const int* __restrict__ offs,       // [NTOT+1], contiguous over (t,g)
    const int* __restrict__ srcperm,
    unsigned short* __restrict__ meanout,
    int grp0, int ngrp)
{
    int gi = blockIdx.x * 16 + (threadIdx.x >> 4);
    if (gi >= ngrp) return;
    int grp = grp0 + gi;
    int l = threadIdx.x & 15;

    int beg = offs[grp];
    int end = offs[grp + 1];
    int m = end - beg;

    int mm = m;
    mm = max(mm, __shfl_xor(mm, 16));
    mm = max(mm, __shfl_xor(mm, 32));

    float a[8];
#pragma unroll
    for (int j = 0; j < 8; ++j) a[j] = 0.f;

    const int eSafe = min(beg, ETOT - 1);
#pragma unroll 4
    for (int i = 0; i < mm; ++i) {
        bool valid = i < m;
        int e = valid ? (beg + i) : eSafe;
        int s = srcperm[e];
        uint4 v = *reinterpret_cast<const uint4*>(
            reinterpret_cast<const char*>(xb) + ((size_t)s << 8) + (l << 4));
        float w = valid ? 1.f : 0.f;
        a[0] += w * __uint_as_float(v.x << 16);
        a[1] += w * __uint_as_float(v.x & 0xFFFF0000u);
        a[2] += w * __uint_as_float(v.y << 16);
        a[3] += w * __uint_as_float(v.y & 0xFFFF0000u);
        a[4] += w * __uint_as_float(v.z << 16);
        a[5] += w * __uint_as_float(v.z & 0xFFFF0000u);
        a[6] += w * __uint_as_float(v.w << 16);
        a[7] += w * __uint_as_float(v.w & 0xFFFF0000u);
    }

    float inv = 1.0f / fmaxf((float)m, 1.0f);
    unsigned int p0, p1, p2, p3;
    asm("v_cvt_pk_bf16_f32 %0, %1, %2" : "=v"(p0) : "v"(a[0] * inv), "v"(a[1] * inv));
    asm("v_cvt_pk_bf16_f32 %0, %1, %2" : "=v"(p1) : "v"(a[2] * inv), "v"(a[3] * inv));
    asm("v_cvt_pk_bf16_f32 %0, %1, %2" : "=v"(p2) : "v"(a[4] * inv), "v"(a[5] * inv));
    asm("v_cvt_pk_bf16_f32 %0, %1, %2" : "=v"(p3) : "v"(a[6] * inv), "v"(a[7] * inv));
    uint4 o = make_uint4(p0, p1, p2, p3);
    *reinterpret_cast<uint4*>(
        reinterpret_cast<char*>(meanout) + ((size_t)gi << 8) + (l << 4)) = o;
}

// ---------------------------------------------------------------------------
// MFMA GEMM: 128 rows/block (2 row-tiles per wave), B staged in LDS,
// XOR-swizzled for conflict-free ds_read_b128.
// ---------------------------------------------------------------------------
__global__ __launch_bounds__(256) void matmul_kernel(
    const unsigned short* __restrict__ meanall, size_t meanStride,
    int t0, int nt,
    const unsigned short* __restrict__ WT,
    const float* __restrict__ bsum,
    float* __restrict__ out, int accum)
{
    __shared__ unsigned short sB[DIM * DIM];   // 32 KB, swizzled

    const int tid = threadIdx.x;
    const int wave = tid >> 6;
    const int lane = tid & 63;
    const int rlo = lane & 15;
    const int khi = lane >> 4;                 // 0..3
    const int row0 = blockIdx.x * 128 + wave * 16;   // tile A rows; tile B = +64

    v4f acc[2][8];
#pragma unroll
    for (int u = 0; u < 2; ++u)
#pragma unroll
        for (int n = 0; n < 8; ++n) acc[u][n] = (v4f){0.f, 0.f, 0.f, 0.f};

    int rowA0 = row0 + rlo;       if (rowA0 >= N_NODES) rowA0 = N_NODES - 1;
    int rowA1 = row0 + 64 + rlo;  if (rowA1 >= N_NODES) rowA1 = N_NODES - 1;

    for (int tt = 0; tt < nt; ++tt) {
        int t = t0 + tt;
        __syncthreads();
        const uint4* gw = reinterpret_cast<const uint4*>(WT + ((size_t)t << 14));
#pragma unroll
        for (int i = 0; i < 8; ++i) {
            int c = tid + (i << 8);            // 0..2047
            uint4 v = gw[c];
            int L = c << 4;
            int row = L >> 8;
            int sb = (row << 8) | ((L & 255) ^ ((row & 7) << 4));
            *reinterpret_cast<uint4*>(reinterpret_cast<char*>(sB) + sb) = v;
        }
        __syncthreads();

        const unsigned short* ar0 = meanall + (size_t)tt * meanStride + ((size_t)rowA0 << 7);
        const unsigned short* ar1 = meanall + (size_t)tt * meanStride + ((size_t)rowA1 << 7);

#pragma unroll
        for (int k0 = 0; k0 < DIM; k0 += 32) {
            v8s a0 = *reinterpret_cast<const v8s*>(ar0 + k0 + (khi << 3));
            v8s a1 = *reinterpret_cast<const v8s*>(ar1 + k0 + (khi << 3));
#pragma unroll
            for (int n = 0; n < 8; ++n) {
                int jrow = (n << 4) | rlo;
                int kb = (k0 + (khi << 3)) << 1;
                int sb = (jrow << 8) | (kb ^ ((jrow & 7) << 4));
                v8s bf = *reinterpret_cast<const v8s*>(reinterpret_cast<char*>(sB) + sb);
                acc[0][n] = __builtin_amdgcn_mfma_f32_16x16x32_bf16(a0, bf, acc[0][n], 0, 0, 0);
                acc[1][n] = __builtin_amdgcn_mfma_f32_16x16x32_bf16(a1, bf, acc[1][n], 0, 0, 0);
            }
        }
    }

    const float inv7 = 1.0f / 7.0f;
#pragma unroll
    for (int u = 0; u < 2; ++u) {
#pragma unroll
        for (int n = 0; n < 8; ++n) {
            int col = (n << 4) | rlo;
            float bs = bsum[col];
#pragma unroll
            for (int r = 0; r < 4; ++r) {
                int row = row0 + u * 64 + (khi << 2) + r;
                if (row < N_NODES) {
                    float* p = out + ((size_t)row << 7) + col;
                    if (accum) *p += acc[u][n][r] * inv7;
                    else       *p = (acc[u][n][r] + bs) * inv7;
                }
            }
        }
    }
}

__global__ __launch_bounds__(256) void out_init_kernel(
    const float* __restrict__ bsum, float* __restrict__ out)
{
    int i = blockIdx.x * 256 + threadIdx.x;
    if (i >= N_NODES * DIM / 4) return;
    int c4 = (i & 31) * 4;
    const float inv7 = 1.0f / 7.0f;
    float4 bv = *reinterpret_cast<const float4*>(bsum + c4);
    float4 o = make_float4(bv.x * inv7, bv.y * inv7, bv.z * inv7, bv.w * inv7);
    reinterpret_cast<float4*>(out)[i] = o;
}

extern "C" void kernel_launch(void* const* d_in, const int* in_sizes, int n_in,
                              void* d_out, int out_size, void* d_ws, size_t ws_size,
                              hipStream_t stream) {
    const float* x  = (const float*)d_in[0];
    const int*   ei = (const int*)d_in[1];     // [N_TYPES, 2, N_EDGES] int32
    const float* W  = (const float*)d_in[2];
    const float* b  = (const float*)d_in[3];
    float* out = (float*)d_out;

    // ---- workspace layout ----
    char* p = (char*)d_ws;
    unsigned short* xb = (unsigned short*)p;          p += (size_t)N_NODES * DIM * 2;       // 25.6 MB
    unsigned short* WT = (unsigned short*)p;          p += (size_t)N_TYPES * DIM * DIM * 2; // 229 KB
    float* bsum = (float*)p;                          p += 512;
    int* srcperm = (int*)p;                           p += (size_t)ETOT * 4;                // 11.2 MB
    int* offs = (int*)p;                              p += (size_t)(NTOT + 1) * 4;          // 2.8 MB
    int* gcur = (int*)p;                              p += (size_t)N_TYPES * BSTRIDE * 4;
    p = (char*)(((uintptr_t)p + 15) & ~(uintptr_t)15);
    unsigned int* bucketbuf = (unsigned int*)p;       // 17.9 MB (dead before meanbuf live)
    unsigned short* meanbuf = (unsigned short*)p;
    size_t mean1_bytes = (size_t)N_NODES * DIM * 2;   // 25.6 MB per type
    size_t used = (size_t)(p - (char*)d_ws);
    size_t bucket_bytes = (size_t)N_TYPES * BSTRIDE * CAP * 4;
    bool fused = (ws_size >= used + 7 * mean1_bytes) &&
                 (7 * mean1_bytes >= bucket_bytes);

    prep_kernel<<<XBLOCKS + 448 + 2, 256, 0, stream>>>(x, W, b, xb, WT, bsum, gcur);
    binpass_kernel<<<N_TYPES * NCHUNKS, 256, 0, stream>>>(ei, gcur, bucketbuf);
    hist_place_kernel<<<NTB, 256, 0, stream>>>(bucketbuf, gcur, offs, srcperm);

    const int matmul_blocks = (N_NODES + 127) / 128;  // 782

    if (fused) {
        size_t meanStride = (size_t)N_NODES * DIM;    // ushorts
        aggregate_kernel<<<(NTOT + 15) / 16, 256, 0, stream>>>(
            xb, offs, srcperm, meanbuf, 0, NTOT);
        matmul_kernel<<<matmul_blocks, 256, 0, stream>>>(
            meanbuf, meanStride, 0, N_TYPES, WT, bsum, out, 0);
    } else {
        out_init_kernel<<<(N_NODES * DIM / 4 + 255) / 256, 256, 0, stream>>>(bsum, out);
        for (int t = 0; t < N_TYPES; ++t) {
            aggregate_kernel<<<(N_NODES + 15) / 16, 256, 0, stream>>>(
                xb, offs, srcperm, meanbuf, t * N_NODES, N_NODES);
            matmul_kernel<<<matmul_blocks, 256, 0, stream>>>(
                meanbuf, 0, t, 1, WT, bsum, out, 1);
        }
    }
}